// Round 1
// 199.476 us; speedup vs baseline: 1.0471x; 1.0471x over previous
//
#include <hip/hip_runtime.h>
#include <cstdint>
#include <cstddef>

#define N_ANCH   120000
#define K_PRE    2000
#define K_POST   512
#define CAP      4096
#define NWORD    32          // ceil(K_PRE/64)
#define HBINS    4096        // top-12-bit histogram
#define IOU_THR  0.7f
#define IMGF     800.0f
#define CLIPV    4.135166556742356f
#define FH       200
#define FW       200
#define FC       256
#define SCALE    0.25f

#define TROWS    96          // scan tile rows (96*256B = 24KB; x2 buffers = 48KB LDS)
#define NTILE    21          // ceil(2000/96); last tile = 80 rows
#define CH       8           // scan chunk rows (register prefetch depth)

#define CG       16          // roi: channels per group (FC/16 -> two time-phased groups per XCD)
#define TPE      4           // rank: threads per element

typedef unsigned long long u64;
// float2 with declared 4B alignment: compiler emits dwordx2; gfx9+ amdhsa
// unaligned-access-mode handles 4B-aligned 8B loads in HW.
typedef float f2u __attribute__((ext_vector_type(2), aligned(4)));

struct Ws {
    uint32_t T;          // (unused — kept for layout stability)
    uint32_t cnt;        // gather counter
    int32_t  nk;         // number kept after NMS
    uint32_t pad;
    u64      combo[CAP];             // (~key)<<32 | index (unsorted)
    float4   cand[K_PRE];            // decoded candidate boxes, score-desc order
    int      rows[K_POST];           // candidate rank per output row, -1 = invalid
    u64      mask[(size_t)K_PRE * NWORD];  // IoU bitmask, ALL 32 words written
    // NOTE: first 16KB of mask doubles as the uint32 hist[4096] (used before mask)
};

// Monotonic float -> uint key (larger float => larger uint). No NaNs expected.
__device__ inline uint32_t fkey(float f) {
    uint32_t u = __float_as_uint(f);
    return (u & 0x80000000u) ? ~u : (u | 0x80000000u);
}

// ---------------------------------------------------------------------------
// Kernel 0: zero the histogram (aliased onto mask region) + counters.
// ---------------------------------------------------------------------------
__global__ __launch_bounds__(1024) void zero_k(Ws* __restrict__ ws) {
    uint32_t* h = (uint32_t*)ws->mask;
    for (int i = threadIdx.x; i < HBINS; i += 1024) h[i] = 0u;
    if (threadIdx.x == 0) { ws->cnt = 0u; ws->nk = 0; ws->T = 0u; }
}

// ---------------------------------------------------------------------------
// Kernel 1: grid-wide 4096-bin histogram of top-12 key bits (LDS-privatized).
// ---------------------------------------------------------------------------
__global__ __launch_bounds__(256) void hist_k(const float* __restrict__ obj,
                                              uint32_t* __restrict__ hist) {
    __shared__ uint32_t h[HBINS];
    for (int i = threadIdx.x; i < HBINS; i += 256) h[i] = 0u;
    __syncthreads();
    const float4* o4 = (const float4*)obj;
    for (int i = blockIdx.x * 256 + threadIdx.x; i < N_ANCH / 4; i += gridDim.x * 256) {
        float4 v = o4[i];
        atomicAdd(&h[fkey(v.x) >> 20], 1u);
        atomicAdd(&h[fkey(v.y) >> 20], 1u);
        atomicAdd(&h[fkey(v.z) >> 20], 1u);
        atomicAdd(&h[fkey(v.w) >> 20], 1u);
    }
    __syncthreads();
    for (int i = threadIdx.x; i < HBINS; i += 256)
        if (h[i]) atomicAdd(&hist[i], h[i]);
}

// ---------------------------------------------------------------------------
// Kernel 2 (fused resolve+gather): each block redundantly computes the
// threshold bucket T from the histogram (4096 L2 reads + block scan, ~2us,
// fully parallel across blocks), then gathers all elements with key >= T
// (float4 loads).
// ---------------------------------------------------------------------------
__global__ __launch_bounds__(256) void gather_k(const float* __restrict__ obj,
                                                const uint32_t* __restrict__ hist,
                                                Ws* __restrict__ ws) {
    __shared__ uint32_t wsum[4];
    __shared__ uint32_t sT;
    const int tid = threadIdx.x;
    const int lane = tid & 63, wave = tid >> 6;
    // ---- per-block threshold resolve: largest bin B with suffix >= K_PRE ----
    uint32_t c[16]; uint32_t s = 0;
#pragma unroll
    for (int k = 0; k < 16; ++k) { c[k] = hist[HBINS - 1 - (16 * tid + k)]; s += c[k]; }
    uint32_t incl = s;
    for (int off = 1; off < 64; off <<= 1) {
        uint32_t t = __shfl_up(incl, off);
        if (lane >= off) incl += t;
    }
    if (lane == 63) wsum[wave] = incl;
    __syncthreads();
    uint32_t wpre = 0;
    for (int w2 = 0; w2 < wave; ++w2) wpre += wsum[w2];
    uint32_t before = wpre + incl - s;
#pragma unroll
    for (int k = 0; k < 16; ++k) {
        uint32_t after = before + c[k];
        if (before < K_PRE && after >= K_PRE)
            sT = (uint32_t)(HBINS - 1 - (16 * tid + k)) << 20;
        before = after;
    }
    __syncthreads();
    const uint32_t T = sT;
    // ---- gather ----
    int i = blockIdx.x * 256 + tid;
    if (i >= N_ANCH / 4) return;
    float4 v = ((const float4*)obj)[i];
    float vals[4] = {v.x, v.y, v.z, v.w};
#pragma unroll
    for (int k = 0; k < 4; ++k) {
        uint32_t u = fkey(vals[k]);
        if (u >= T) {
            uint32_t pos = atomicAdd(&ws->cnt, 1u);
            if (pos < CAP)
                ws->combo[pos] = ((u64)(~u) << 32) | (uint32_t)(4 * i + k);
        }
    }
}

// ---------------------------------------------------------------------------
// Kernel 3: RANK-based ordering. Combos are distinct, so sorted position ==
// rank == #{j: combo[j] < combo[i]} (= score desc, index asc — exact
// lax.top_k order). TPE=4 threads per element count strided quarters over
// LDS-staged combos; winner decodes straight into cand[rank].
// ---------------------------------------------------------------------------
__global__ __launch_bounds__(256) void rank_decode_k(const float* __restrict__ deltas,
                                                     const float* __restrict__ anchors,
                                                     Ws* __restrict__ ws) {
    __shared__ u64 sc[CAP];
    const int tid = threadIdx.x;
    int M = (int)ws->cnt;
    if (M > CAP) M = CAP;
    const int ebase = blockIdx.x * (256 / TPE);
    if (ebase >= M) return;
    for (int e = tid; e < M; e += 256) sc[e] = ws->combo[e];
    __syncthreads();
    const int gid = ebase + tid / TPE;
    const int sub = tid & (TPE - 1);
    if (gid >= M) return;
    const u64 mine = sc[gid];
    int cnt = 0;
    int j = sub;
    for (; j + 3 * TPE < M; j += 4 * TPE) {
        u64 a = sc[j], b = sc[j + TPE], c = sc[j + 2 * TPE], d = sc[j + 3 * TPE];
        cnt += (int)(a < mine) + (int)(b < mine) + (int)(c < mine) + (int)(d < mine);
    }
    for (; j < M; j += TPE) cnt += (int)(sc[j] < mine);
    cnt += __shfl_xor(cnt, 1);
    cnt += __shfl_xor(cnt, 2);
    if (sub == 0 && cnt < K_PRE) {
        const uint32_t idx = (uint32_t)(mine & 0xFFFFFFFFull);
        float a0 = anchors[idx * 4 + 0], a1 = anchors[idx * 4 + 1];
        float a2 = anchors[idx * 4 + 2], a3 = anchors[idx * 4 + 3];
        float d0 = deltas[idx * 4 + 0],  d1 = deltas[idx * 4 + 1];
        float d2 = fminf(deltas[idx * 4 + 2], CLIPV);
        float d3 = fminf(deltas[idx * 4 + 3], CLIPV);
        float w = a2 - a0, h = a3 - a1;
        float cx = a0 + 0.5f * w, cy = a1 + 0.5f * h;
        float pcx = d0 * w + cx, pcy = d1 * h + cy;
        float pw = expf(d2) * w, ph = expf(d3) * h;
        float x1 = fminf(fmaxf(pcx - 0.5f * pw, 0.0f), IMGF);
        float y1 = fminf(fmaxf(pcy - 0.5f * ph, 0.0f), IMGF);
        float x2 = fminf(fmaxf(pcx + 0.5f * pw, 0.0f), IMGF);
        float y2 = fminf(fmaxf(pcy + 0.5f * ph, 0.0f), IMGF);
        ws->cand[cnt] = make_float4(x1, y1, x2, y2);
    }
}

// ---------------------------------------------------------------------------
// Kernel 4: build the pairwise suppression bitmask.
// ---------------------------------------------------------------------------
__global__ __launch_bounds__(256) void nms_mask_k(Ws* __restrict__ ws) {
    const int i = blockIdx.x;
    const int lane = threadIdx.x & 63;
    const int wave = threadIdx.x >> 6;
    const float4 bi = ws->cand[i];
    const float ai = (bi.z - bi.x) * (bi.w - bi.y);
    for (int wd = wave; wd < NWORD; wd += 4) {
        int j = wd * 64 + lane;
        bool bit = false;
        if (j < K_PRE && j > i) {
            float4 bj = ws->cand[j];
            float aj = (bj.z - bj.x) * (bj.w - bj.y);
            float xx1 = fmaxf(bi.x, bj.x);
            float yy1 = fmaxf(bi.y, bj.y);
            float xx2 = fminf(bi.z, bj.z);
            float yy2 = fminf(bi.w, bj.w);
            float ww = fmaxf(xx2 - xx1, 0.0f);
            float hh = fmaxf(yy2 - yy1, 0.0f);
            float inter = ww * hh;
            float iou = inter / (ai + aj - inter + 1e-6f);
            bit = iou > IOU_THR;
        }
        u64 bal = __ballot(bit);
        if (lane == 0) ws->mask[(size_t)i * NWORD + wd] = bal;
    }
}

// ---------------------------------------------------------------------------
// Kernel 5: greedy scan, owner-lane formulation + early exit once K_POST
// rows are kept (downstream only consumes the first K_POST kept rows).
// ---------------------------------------------------------------------------
__global__ __launch_bounds__(512) void nms_scan_k(Ws* __restrict__ ws) {
    __shared__ __align__(16) u64 sbuf[2][TROWS * NWORD];
    __shared__ int s_stop;
    const int tid = threadIdx.x;
    const int lane = tid & 63;
    const int wave = tid >> 6;
    const int lmod = lane & 31;
    const u64* __restrict__ mask = ws->mask;

    {
        const ulonglong2* src = (const ulonglong2*)mask;
        ulonglong2* dst = (ulonglong2*)sbuf[0];
        for (int e = tid; e < TROWS * NWORD / 2; e += 512) dst[e] = src[e];
    }
    if (tid == 0) s_stop = 0;
    __syncthreads();

    u64 supp = 0ull;
    int kcnt = 0;
    int decided = 0;
    for (int t = 0; t < NTILE; ++t) {
        const int base = t * TROWS;
        const int nb = min(TROWS, K_PRE - base);
        if (wave == 0) {
            const u64* sm = sbuf[t & 1];
            u64 A[CH], B[CH];
#pragma unroll
            for (int b = 0; b < CH; ++b) A[b] = sm[b * NWORD + lmod];
            for (int s = 0; s < nb; s += 2 * CH) {
                const bool hasB = (s + CH) < nb;
                if (hasB) {
#pragma unroll
                    for (int b = 0; b < CH; ++b) B[b] = sm[(s + CH + b) * NWORD + lmod];
                }
                {
                    const int w = (base + s) >> 6;
                    const int bofs = (base + s) & 63;
                    u64 keptw = 0ull;
                    if (lane == w) {
                        u64 cur = supp;
#pragma unroll
                        for (int b = 0; b < CH; ++b) {
                            u64 bit = (cur >> (bofs + b)) & 1ull;
                            u64 sel = bit - 1ull;
                            cur |= A[b] & sel;
                            keptw |= sel & (1ull << b);
                        }
                        supp = cur;
                    }
                    u64 kb = __shfl(keptw, w);
                    kcnt += __popcll(kb);
#pragma unroll
                    for (int b = 0; b < CH; ++b) {
                        u64 sel = 0ull - ((kb >> b) & 1ull);
                        supp |= A[b] & sel;
                    }
                }
                if (hasB) {
                    if (s + 2 * CH < nb) {
#pragma unroll
                        for (int b = 0; b < CH; ++b)
                            A[b] = sm[(s + 2 * CH + b) * NWORD + lmod];
                    }
                    const int w = (base + s + CH) >> 6;
                    const int bofs = (base + s + CH) & 63;
                    u64 keptw = 0ull;
                    if (lane == w) {
                        u64 cur = supp;
#pragma unroll
                        for (int b = 0; b < CH; ++b) {
                            u64 bit = (cur >> (bofs + b)) & 1ull;
                            u64 sel = bit - 1ull;
                            cur |= B[b] & sel;
                            keptw |= sel & (1ull << b);
                        }
                        supp = cur;
                    }
                    u64 kb = __shfl(keptw, w);
                    kcnt += __popcll(kb);
#pragma unroll
                    for (int b = 0; b < CH; ++b) {
                        u64 sel = 0ull - ((kb >> b) & 1ull);
                        supp |= B[b] & sel;
                    }
                }
            }
            decided = base + nb;
            if (lane == 0 && kcnt >= K_POST) s_stop = 1;
        } else if (t + 1 < NTILE) {
            const int nbase = (t + 1) * TROWS;
            const int npairs = (min(TROWS, K_PRE - nbase) * NWORD) / 2;
            const ulonglong2* src = (const ulonglong2*)(mask + (size_t)nbase * NWORD);
            ulonglong2* dst = (ulonglong2*)sbuf[(t + 1) & 1];
            for (int e = tid - 64; e < npairs; e += 448) dst[e] = src[e];
        }
        __syncthreads();
        if (s_stop) break;
    }

    if (wave == 0) {
        u64 valid;
        if (lane < NWORD - 1)       valid = ~0ull;
        else if (lane == NWORD - 1) valid = (1ull << (K_PRE - (NWORD - 1) * 64)) - 1ull;
        else                        valid = 0ull;
        const int dw = decided - lane * 64;
        const u64 dmask = (dw <= 0) ? 0ull : ((dw >= 64) ? ~0ull : ((1ull << dw) - 1ull));
        u64 keepw = (~supp) & valid & dmask;
        int cnt = __popcll(keepw);
        int incl = cnt;
        for (int off = 1; off < 64; off <<= 1) {
            int t = __shfl_up(incl, off);
            if (lane >= off) incl += t;
        }
        int pos = incl - cnt;
        u64 kw = keepw;
        while (kw) {
            int b = __ffsll((unsigned long long)kw) - 1;
            kw &= kw - 1ull;
            if (pos < K_POST) ws->rows[pos] = lane * 64 + b;
            ++pos;
        }
        int total = __shfl(incl, 63);
        if (lane == 0) ws->nk = total;
        int start = total < K_POST ? total : K_POST;
        for (int r = start + lane; r < K_POST; r += 64) ws->rows[r] = -1;
    }
}

// ---------------------------------------------------------------------------
// Kernel 6: ROIAlign. Round-11 changes:
//  (a) Exact channel coverage: cslot in [0,5), channels {cslot, cslot+5,
//      cslot+10, cslot+15} over CG=16 — covers 0..15 exactly once. The old
//      CG=32/40-slot mapping issued 20% dummy loads (channels 32-39 -> ch 0,
//      result discarded). The 4th channel is valid only for cslot==0 and is
//      exec-mask-skipped (no traffic for masked lanes).
//  (b) L2-resident phased channel groups: grid 16*K_POST; xcd = b&7,
//      s = b>>3; phase p = s>>9 gives XCD x channels [16*(x+8p), +16) =
//      2.56 MB slice (< 4 MB L2; old 32-ch slice was 5.12 MB -> thrash,
//      FETCH 64 MB vs 41 MB feature). In-order round-robin dispatch keeps
//      the two phases time-separated (~1500 resident blocks << 4096/phase).
// ---------------------------------------------------------------------------
__global__ __launch_bounds__(256) void roi_k(const float* __restrict__ feat,
                                             const Ws* __restrict__ ws,
                                             float* __restrict__ out) {
    const int b = blockIdx.x;
    const int xcd = b & 7;                  // round-robin XCD id (heuristic)
    const int s = b >> 3;                   // per-XCD sequence index
    const int r = s & (K_POST - 1);         // roi
    const int cg = xcd + 8 * (s >> 9);      // channel group: phase 0 -> x, phase 1 -> x+8
    const int cbase = cg * CG;
    float* oblk = out + (size_t)r * (FC * 49) + (size_t)cbase * 49;
    const int row = ws->rows[r];
    const int tid = threadIdx.x;

    if (row < 0) {
        for (int e = tid; e < CG * 49; e += 256) oblk[e] = 0.0f;
        return;
    }
    if (tid >= 245) return;                 // 5 channel slots x 49 bins

    const int p = tid % 49;
    const int cslot = tid / 49;             // 0..4
    const int oy = p / 7, ox = p % 7;

    const float4 bx = ws->cand[row];
    const float x1 = bx.x * SCALE, y1 = bx.y * SCALE;
    const float x2 = bx.z * SCALE, y2 = bx.w * SCALE;
    const float rw = fmaxf(x2 - x1, 1.0f);
    const float rh = fmaxf(y2 - y1, 1.0f);
    const float stepx = rw / 14.0f;
    const float stepy = rh / 14.0f;

    int    off0[4], off1[4];                // row-iy0 / row-iy1 base offsets
    float4 w4[4];                           // (w00,w01,w10,w11) * 0.25
#pragma unroll
    for (int sub = 0; sub < 4; ++sub) {
        const int sy = sub >> 1, sx = sub & 1;
        float yy = y1 + ((float)(2 * oy + sy) + 0.5f) * stepy;
        float y = fminf(fmaxf(yy, 0.0f), (float)(FH - 1));
        float fy0 = floorf(y);
        int iy0 = (int)fy0;
        int iy1 = min(iy0 + 1, FH - 1);
        float ly = y - fy0;
        float xx = x1 + ((float)(2 * ox + sx) + 0.5f) * stepx;
        float x = fminf(fmaxf(xx, 0.0f), (float)(FW - 1));
        float fx0 = floorf(x);
        int ix0 = (int)fx0;
        float lx = x - fx0;
        float wxl, wxr; int base;
        if (ix0 >= FW - 1) { base = FW - 2; wxl = 0.0f; wxr = 1.0f; } // lx==0 here
        else               { base = ix0;    wxl = 1.0f - lx; wxr = lx; }
        float wy0 = 1.0f - ly, wy1 = ly;
        off0[sub] = iy0 * FW + base;
        off1[sub] = iy1 * FW + base;
        w4[sub] = make_float4(wy0 * wxl * 0.25f, wy0 * wxr * 0.25f,
                              wy1 * wxl * 0.25f, wy1 * wxr * 0.25f);
    }

    // ---- pair 1: channels cslot, cslot+5 (always valid) — 16 loads in flight
    {
        const int c0 = cslot;
        const int c1 = cslot + 5;
        const float* f0 = feat + (size_t)(cbase + c0) * (FH * FW);
        const float* f1 = feat + (size_t)(cbase + c1) * (FH * FW);
        f2u r0[8], r1[8];
#pragma unroll
        for (int sub = 0; sub < 4; ++sub) {
            r0[2 * sub]     = *(const f2u*)(f0 + off0[sub]);
            r0[2 * sub + 1] = *(const f2u*)(f0 + off1[sub]);
            r1[2 * sub]     = *(const f2u*)(f1 + off0[sub]);
            r1[2 * sub + 1] = *(const f2u*)(f1 + off1[sub]);
        }
        float a0 = 0.0f, a1 = 0.0f;
#pragma unroll
        for (int sub = 0; sub < 4; ++sub) {
            a0 += w4[sub].x * r0[2 * sub].x + w4[sub].y * r0[2 * sub].y
                + w4[sub].z * r0[2 * sub + 1].x + w4[sub].w * r0[2 * sub + 1].y;
            a1 += w4[sub].x * r1[2 * sub].x + w4[sub].y * r1[2 * sub].y
                + w4[sub].z * r1[2 * sub + 1].x + w4[sub].w * r1[2 * sub + 1].y;
        }
        oblk[c0 * 49 + p] = a0;
        oblk[c1 * 49 + p] = a1;
    }

    // ---- pair 2: channel cslot+10 (always valid) + cslot+15 (cslot==0 only)
    {
        const int c2 = cslot + 10;
        const float* f2 = feat + (size_t)(cbase + c2) * (FH * FW);
        f2u r2[8];
#pragma unroll
        for (int sub = 0; sub < 4; ++sub) {
            r2[2 * sub]     = *(const f2u*)(f2 + off0[sub]);
            r2[2 * sub + 1] = *(const f2u*)(f2 + off1[sub]);
        }
        float a2 = 0.0f;
#pragma unroll
        for (int sub = 0; sub < 4; ++sub) {
            a2 += w4[sub].x * r2[2 * sub].x + w4[sub].y * r2[2 * sub].y
                + w4[sub].z * r2[2 * sub + 1].x + w4[sub].w * r2[2 * sub + 1].y;
        }
        oblk[c2 * 49 + p] = a2;

        if (cslot == 0) {                   // exec-masked: no traffic for cslot>0
            const int c3 = 15;
            const float* f3 = feat + (size_t)(cbase + c3) * (FH * FW);
            f2u r3[8];
#pragma unroll
            for (int sub = 0; sub < 4; ++sub) {
                r3[2 * sub]     = *(const f2u*)(f3 + off0[sub]);
                r3[2 * sub + 1] = *(const f2u*)(f3 + off1[sub]);
            }
            float a3 = 0.0f;
#pragma unroll
            for (int sub = 0; sub < 4; ++sub) {
                a3 += w4[sub].x * r3[2 * sub].x + w4[sub].y * r3[2 * sub].y
                    + w4[sub].z * r3[2 * sub + 1].x + w4[sub].w * r3[2 * sub + 1].y;
            }
            oblk[c3 * 49 + p] = a3;
        }
    }
}

extern "C" void kernel_launch(void* const* d_in, const int* in_sizes, int n_in,
                              void* d_out, int out_size, void* d_ws, size_t ws_size,
                              hipStream_t stream) {
    const float* feature    = (const float*)d_in[0];
    const float* objectness = (const float*)d_in[1];
    const float* deltas     = (const float*)d_in[2];
    const float* anchors    = (const float*)d_in[3];
    Ws* ws = (Ws*)d_ws;
    uint32_t* hist = (uint32_t*)ws->mask;   // alias: hist lives in (pre-)mask space
    float* out = (float*)d_out;

    hipLaunchKernelGGL(zero_k, dim3(1), dim3(1024), 0, stream, ws);
    hipLaunchKernelGGL(hist_k, dim3(256), dim3(256), 0, stream, objectness, hist);
    hipLaunchKernelGGL(gather_k, dim3((N_ANCH / 4 + 255) / 256), dim3(256), 0, stream,
                       objectness, hist, ws);
    hipLaunchKernelGGL(rank_decode_k, dim3(CAP / (256 / TPE)), dim3(256), 0, stream,
                       deltas, anchors, ws);
    hipLaunchKernelGGL(nms_mask_k, dim3(K_PRE), dim3(256), 0, stream, ws);
    hipLaunchKernelGGL(nms_scan_k, dim3(1), dim3(512), 0, stream, ws);
    hipLaunchKernelGGL(roi_k, dim3(16 * K_POST), dim3(256), 0, stream, feature, ws, out);
}

// Round 2
// 195.200 us; speedup vs baseline: 1.0700x; 1.0219x over previous
//
#include <hip/hip_runtime.h>
#include <cstdint>
#include <cstddef>

#define N_ANCH   120000
#define K_PRE    2000
#define K_POST   512
#define CAP      4096
#define NWORD    32          // ceil(K_PRE/64)
#define HBINS    4096        // top-12-bit histogram
#define IOU_THR  0.7f
#define IMGF     800.0f
#define CLIPV    4.135166556742356f
#define FH       200
#define FW       200
#define FC       256
#define SCALE    0.25f

#define TROWS    96          // scan tile rows (96*256B = 24KB; x2 buffers = 48KB LDS)
#define NTILE    21          // ceil(2000/96); last tile = 80 rows
#define CH       8           // scan chunk rows (register prefetch depth)

#define CG       16          // roi: channels per group (FC/16 -> two time-phased groups per XCD)
#define TPE      4           // rank: threads per element

typedef unsigned long long u64;
// float2 with declared 4B alignment: compiler emits dwordx2; gfx9+ amdhsa
// unaligned-access-mode handles 4B-aligned 8B loads in HW.
typedef float f2u __attribute__((ext_vector_type(2), aligned(4)));

struct Ws {
    uint32_t T;          // (unused — kept for layout stability)
    uint32_t cnt;        // gather counter
    int32_t  nk;         // number kept after NMS
    uint32_t pad;
    u64      combo[CAP];             // (~key)<<32 | index (unsorted)
    float4   cand[K_PRE];            // decoded candidate boxes, score-desc order
    int      rows[K_POST];           // candidate rank per output row, -1 = invalid
    u64      mask[(size_t)K_PRE * NWORD];  // IoU bitmask, ALL 32 words written
    // NOTE: first 16KB of mask doubles as the uint32 hist[4096] (used before mask)
};

// Monotonic float -> uint key (larger float => larger uint). No NaNs expected.
__device__ inline uint32_t fkey(float f) {
    uint32_t u = __float_as_uint(f);
    return (u & 0x80000000u) ? ~u : (u | 0x80000000u);
}

// ---------------------------------------------------------------------------
// Kernel 0: zero the histogram (aliased onto mask region) + counters.
// ---------------------------------------------------------------------------
__global__ __launch_bounds__(1024) void zero_k(Ws* __restrict__ ws) {
    uint32_t* h = (uint32_t*)ws->mask;
    for (int i = threadIdx.x; i < HBINS; i += 1024) h[i] = 0u;
    if (threadIdx.x == 0) { ws->cnt = 0u; ws->nk = 0; ws->T = 0u; }
}

// ---------------------------------------------------------------------------
// Kernel 1: grid-wide 4096-bin histogram of top-12 key bits (LDS-privatized).
// ---------------------------------------------------------------------------
__global__ __launch_bounds__(256) void hist_k(const float* __restrict__ obj,
                                              uint32_t* __restrict__ hist) {
    __shared__ uint32_t h[HBINS];
    for (int i = threadIdx.x; i < HBINS; i += 256) h[i] = 0u;
    __syncthreads();
    const float4* o4 = (const float4*)obj;
    for (int i = blockIdx.x * 256 + threadIdx.x; i < N_ANCH / 4; i += gridDim.x * 256) {
        float4 v = o4[i];
        atomicAdd(&h[fkey(v.x) >> 20], 1u);
        atomicAdd(&h[fkey(v.y) >> 20], 1u);
        atomicAdd(&h[fkey(v.z) >> 20], 1u);
        atomicAdd(&h[fkey(v.w) >> 20], 1u);
    }
    __syncthreads();
    for (int i = threadIdx.x; i < HBINS; i += 256)
        if (h[i]) atomicAdd(&hist[i], h[i]);
}

// ---------------------------------------------------------------------------
// Kernel 2 (fused resolve+gather): each block redundantly computes the
// threshold bucket T from the histogram (4096 L2 reads + block scan, ~2us,
// fully parallel across blocks), then gathers all elements with key >= T
// (float4 loads).
// ---------------------------------------------------------------------------
__global__ __launch_bounds__(256) void gather_k(const float* __restrict__ obj,
                                                const uint32_t* __restrict__ hist,
                                                Ws* __restrict__ ws) {
    __shared__ uint32_t wsum[4];
    __shared__ uint32_t sT;
    const int tid = threadIdx.x;
    const int lane = tid & 63, wave = tid >> 6;
    // ---- per-block threshold resolve: largest bin B with suffix >= K_PRE ----
    uint32_t c[16]; uint32_t s = 0;
#pragma unroll
    for (int k = 0; k < 16; ++k) { c[k] = hist[HBINS - 1 - (16 * tid + k)]; s += c[k]; }
    uint32_t incl = s;
    for (int off = 1; off < 64; off <<= 1) {
        uint32_t t = __shfl_up(incl, off);
        if (lane >= off) incl += t;
    }
    if (lane == 63) wsum[wave] = incl;
    __syncthreads();
    uint32_t wpre = 0;
    for (int w2 = 0; w2 < wave; ++w2) wpre += wsum[w2];
    uint32_t before = wpre + incl - s;
#pragma unroll
    for (int k = 0; k < 16; ++k) {
        uint32_t after = before + c[k];
        if (before < K_PRE && after >= K_PRE)
            sT = (uint32_t)(HBINS - 1 - (16 * tid + k)) << 20;
        before = after;
    }
    __syncthreads();
    const uint32_t T = sT;
    // ---- gather ----
    int i = blockIdx.x * 256 + tid;
    if (i >= N_ANCH / 4) return;
    float4 v = ((const float4*)obj)[i];
    float vals[4] = {v.x, v.y, v.z, v.w};
#pragma unroll
    for (int k = 0; k < 4; ++k) {
        uint32_t u = fkey(vals[k]);
        if (u >= T) {
            uint32_t pos = atomicAdd(&ws->cnt, 1u);
            if (pos < CAP)
                ws->combo[pos] = ((u64)(~u) << 32) | (uint32_t)(4 * i + k);
        }
    }
}

// ---------------------------------------------------------------------------
// Kernel 3: RANK-based ordering. Combos are distinct, so sorted position ==
// rank == #{j: combo[j] < combo[i]} (= score desc, index asc — exact
// lax.top_k order). TPE=4 threads per element count strided quarters over
// LDS-staged combos; winner decodes straight into cand[rank].
// ---------------------------------------------------------------------------
__global__ __launch_bounds__(256) void rank_decode_k(const float* __restrict__ deltas,
                                                     const float* __restrict__ anchors,
                                                     Ws* __restrict__ ws) {
    __shared__ u64 sc[CAP];
    const int tid = threadIdx.x;
    int M = (int)ws->cnt;
    if (M > CAP) M = CAP;
    const int ebase = blockIdx.x * (256 / TPE);
    if (ebase >= M) return;
    for (int e = tid; e < M; e += 256) sc[e] = ws->combo[e];
    __syncthreads();
    const int gid = ebase + tid / TPE;
    const int sub = tid & (TPE - 1);
    if (gid >= M) return;
    const u64 mine = sc[gid];
    int cnt = 0;
    int j = sub;
    for (; j + 3 * TPE < M; j += 4 * TPE) {
        u64 a = sc[j], b = sc[j + TPE], c = sc[j + 2 * TPE], d = sc[j + 3 * TPE];
        cnt += (int)(a < mine) + (int)(b < mine) + (int)(c < mine) + (int)(d < mine);
    }
    for (; j < M; j += TPE) cnt += (int)(sc[j] < mine);
    cnt += __shfl_xor(cnt, 1);
    cnt += __shfl_xor(cnt, 2);
    if (sub == 0 && cnt < K_PRE) {
        const uint32_t idx = (uint32_t)(mine & 0xFFFFFFFFull);
        float a0 = anchors[idx * 4 + 0], a1 = anchors[idx * 4 + 1];
        float a2 = anchors[idx * 4 + 2], a3 = anchors[idx * 4 + 3];
        float d0 = deltas[idx * 4 + 0],  d1 = deltas[idx * 4 + 1];
        float d2 = fminf(deltas[idx * 4 + 2], CLIPV);
        float d3 = fminf(deltas[idx * 4 + 3], CLIPV);
        float w = a2 - a0, h = a3 - a1;
        float cx = a0 + 0.5f * w, cy = a1 + 0.5f * h;
        float pcx = d0 * w + cx, pcy = d1 * h + cy;
        float pw = expf(d2) * w, ph = expf(d3) * h;
        float x1 = fminf(fmaxf(pcx - 0.5f * pw, 0.0f), IMGF);
        float y1 = fminf(fmaxf(pcy - 0.5f * ph, 0.0f), IMGF);
        float x2 = fminf(fmaxf(pcx + 0.5f * pw, 0.0f), IMGF);
        float y2 = fminf(fmaxf(pcy + 0.5f * ph, 0.0f), IMGF);
        ws->cand[cnt] = make_float4(x1, y1, x2, y2);
    }
}

// ---------------------------------------------------------------------------
// Kernel 4: build the pairwise suppression bitmask.
// ---------------------------------------------------------------------------
__global__ __launch_bounds__(256) void nms_mask_k(Ws* __restrict__ ws) {
    const int i = blockIdx.x;
    const int lane = threadIdx.x & 63;
    const int wave = threadIdx.x >> 6;
    const float4 bi = ws->cand[i];
    const float ai = (bi.z - bi.x) * (bi.w - bi.y);
    for (int wd = wave; wd < NWORD; wd += 4) {
        int j = wd * 64 + lane;
        bool bit = false;
        if (j < K_PRE && j > i) {
            float4 bj = ws->cand[j];
            float aj = (bj.z - bj.x) * (bj.w - bj.y);
            float xx1 = fmaxf(bi.x, bj.x);
            float yy1 = fmaxf(bi.y, bj.y);
            float xx2 = fminf(bi.z, bj.z);
            float yy2 = fminf(bi.w, bj.w);
            float ww = fmaxf(xx2 - xx1, 0.0f);
            float hh = fmaxf(yy2 - yy1, 0.0f);
            float inter = ww * hh;
            float iou = inter / (ai + aj - inter + 1e-6f);
            bit = iou > IOU_THR;
        }
        u64 bal = __ballot(bit);
        if (lane == 0) ws->mask[(size_t)i * NWORD + wd] = bal;
    }
}

// ---------------------------------------------------------------------------
// Kernel 5: greedy scan, owner-lane formulation + early exit once K_POST
// rows are kept (downstream only consumes the first K_POST kept rows).
// ---------------------------------------------------------------------------
__global__ __launch_bounds__(512) void nms_scan_k(Ws* __restrict__ ws) {
    __shared__ __align__(16) u64 sbuf[2][TROWS * NWORD];
    __shared__ int s_stop;
    const int tid = threadIdx.x;
    const int lane = tid & 63;
    const int wave = tid >> 6;
    const int lmod = lane & 31;
    const u64* __restrict__ mask = ws->mask;

    {
        const ulonglong2* src = (const ulonglong2*)mask;
        ulonglong2* dst = (ulonglong2*)sbuf[0];
        for (int e = tid; e < TROWS * NWORD / 2; e += 512) dst[e] = src[e];
    }
    if (tid == 0) s_stop = 0;
    __syncthreads();

    u64 supp = 0ull;
    int kcnt = 0;
    int decided = 0;
    for (int t = 0; t < NTILE; ++t) {
        const int base = t * TROWS;
        const int nb = min(TROWS, K_PRE - base);
        if (wave == 0) {
            const u64* sm = sbuf[t & 1];
            u64 A[CH], B[CH];
#pragma unroll
            for (int b = 0; b < CH; ++b) A[b] = sm[b * NWORD + lmod];
            for (int s = 0; s < nb; s += 2 * CH) {
                const bool hasB = (s + CH) < nb;
                if (hasB) {
#pragma unroll
                    for (int b = 0; b < CH; ++b) B[b] = sm[(s + CH + b) * NWORD + lmod];
                }
                {
                    const int w = (base + s) >> 6;
                    const int bofs = (base + s) & 63;
                    u64 keptw = 0ull;
                    if (lane == w) {
                        u64 cur = supp;
#pragma unroll
                        for (int b = 0; b < CH; ++b) {
                            u64 bit = (cur >> (bofs + b)) & 1ull;
                            u64 sel = bit - 1ull;
                            cur |= A[b] & sel;
                            keptw |= sel & (1ull << b);
                        }
                        supp = cur;
                    }
                    u64 kb = __shfl(keptw, w);
                    kcnt += __popcll(kb);
#pragma unroll
                    for (int b = 0; b < CH; ++b) {
                        u64 sel = 0ull - ((kb >> b) & 1ull);
                        supp |= A[b] & sel;
                    }
                }
                if (hasB) {
                    if (s + 2 * CH < nb) {
#pragma unroll
                        for (int b = 0; b < CH; ++b)
                            A[b] = sm[(s + 2 * CH + b) * NWORD + lmod];
                    }
                    const int w = (base + s + CH) >> 6;
                    const int bofs = (base + s + CH) & 63;
                    u64 keptw = 0ull;
                    if (lane == w) {
                        u64 cur = supp;
#pragma unroll
                        for (int b = 0; b < CH; ++b) {
                            u64 bit = (cur >> (bofs + b)) & 1ull;
                            u64 sel = bit - 1ull;
                            cur |= B[b] & sel;
                            keptw |= sel & (1ull << b);
                        }
                        supp = cur;
                    }
                    u64 kb = __shfl(keptw, w);
                    kcnt += __popcll(kb);
#pragma unroll
                    for (int b = 0; b < CH; ++b) {
                        u64 sel = 0ull - ((kb >> b) & 1ull);
                        supp |= B[b] & sel;
                    }
                }
            }
            decided = base + nb;
            if (lane == 0 && kcnt >= K_POST) s_stop = 1;
        } else if (t + 1 < NTILE) {
            const int nbase = (t + 1) * TROWS;
            const int npairs = (min(TROWS, K_PRE - nbase) * NWORD) / 2;
            const ulonglong2* src = (const ulonglong2*)(mask + (size_t)nbase * NWORD);
            ulonglong2* dst = (ulonglong2*)sbuf[(t + 1) & 1];
            for (int e = tid - 64; e < npairs; e += 448) dst[e] = src[e];
        }
        __syncthreads();
        if (s_stop) break;
    }

    if (wave == 0) {
        u64 valid;
        if (lane < NWORD - 1)       valid = ~0ull;
        else if (lane == NWORD - 1) valid = (1ull << (K_PRE - (NWORD - 1) * 64)) - 1ull;
        else                        valid = 0ull;
        const int dw = decided - lane * 64;
        const u64 dmask = (dw <= 0) ? 0ull : ((dw >= 64) ? ~0ull : ((1ull << dw) - 1ull));
        u64 keepw = (~supp) & valid & dmask;
        int cnt = __popcll(keepw);
        int incl = cnt;
        for (int off = 1; off < 64; off <<= 1) {
            int t = __shfl_up(incl, off);
            if (lane >= off) incl += t;
        }
        int pos = incl - cnt;
        u64 kw = keepw;
        while (kw) {
            int b = __ffsll((unsigned long long)kw) - 1;
            kw &= kw - 1ull;
            if (pos < K_POST) ws->rows[pos] = lane * 64 + b;
            ++pos;
        }
        int total = __shfl(incl, 63);
        if (lane == 0) ws->nk = total;
        int start = total < K_POST ? total : K_POST;
        for (int r = start + lane; r < K_POST; r += 64) ws->rows[r] = -1;
    }
}

// ---------------------------------------------------------------------------
// Kernel 6: ROIAlign. Round-12 change: MAXIMUM MLP — all 24-32 per-thread
// scattered loads (r0,r1,r2 + exec-masked r3 for cslot==0) issue back-to-back
// BEFORE any FMA. Round-11 had three dependent load->wait->FMA phases
// (16/8/8 in flight), each eating a full L2-latency window; counters showed
// latency-bound (HBM 11%, VALU 23%, occupancy 41%, TA ~50% busy). In-order
// vmcnt retirement lets r0's FMAs start at vmcnt(24) while r1/r2/r3 are
// still in flight — one latency exposure instead of three. VGPR ~48->~110
// (still 4 waves/SIMD = 16/CU > measured 13 resident).
// Keeps round-11's exact channel coverage (cslot in [0,5) -> {c,c+5,c+10}
// + cslot==0 -> 15) and L2-phased channel groups (2.56 MB/XCD slice).
// ---------------------------------------------------------------------------
__global__ __launch_bounds__(256) void roi_k(const float* __restrict__ feat,
                                             const Ws* __restrict__ ws,
                                             float* __restrict__ out) {
    const int b = blockIdx.x;
    const int xcd = b & 7;                  // round-robin XCD id (heuristic)
    const int s = b >> 3;                   // per-XCD sequence index
    const int r = s & (K_POST - 1);         // roi
    const int cg = xcd + 8 * (s >> 9);      // channel group: phase 0 -> x, phase 1 -> x+8
    const int cbase = cg * CG;
    float* oblk = out + (size_t)r * (FC * 49) + (size_t)cbase * 49;
    const int row = ws->rows[r];
    const int tid = threadIdx.x;

    if (row < 0) {
        for (int e = tid; e < CG * 49; e += 256) oblk[e] = 0.0f;
        return;
    }
    if (tid >= 245) return;                 // 5 channel slots x 49 bins

    const int p = tid % 49;
    const int cslot = tid / 49;             // 0..4
    const int oy = p / 7, ox = p % 7;

    const float4 bx = ws->cand[row];
    const float x1 = bx.x * SCALE, y1 = bx.y * SCALE;
    const float x2 = bx.z * SCALE, y2 = bx.w * SCALE;
    const float rw = fmaxf(x2 - x1, 1.0f);
    const float rh = fmaxf(y2 - y1, 1.0f);
    const float stepx = rw / 14.0f;
    const float stepy = rh / 14.0f;

    int    off0[4], off1[4];                // row-iy0 / row-iy1 base offsets
    float4 w4[4];                           // (w00,w01,w10,w11) * 0.25
#pragma unroll
    for (int sub = 0; sub < 4; ++sub) {
        const int sy = sub >> 1, sx = sub & 1;
        float yy = y1 + ((float)(2 * oy + sy) + 0.5f) * stepy;
        float y = fminf(fmaxf(yy, 0.0f), (float)(FH - 1));
        float fy0 = floorf(y);
        int iy0 = (int)fy0;
        int iy1 = min(iy0 + 1, FH - 1);
        float ly = y - fy0;
        float xx = x1 + ((float)(2 * ox + sx) + 0.5f) * stepx;
        float x = fminf(fmaxf(xx, 0.0f), (float)(FW - 1));
        float fx0 = floorf(x);
        int ix0 = (int)fx0;
        float lx = x - fx0;
        float wxl, wxr; int base;
        if (ix0 >= FW - 1) { base = FW - 2; wxl = 0.0f; wxr = 1.0f; } // lx==0 here
        else               { base = ix0;    wxl = 1.0f - lx; wxr = lx; }
        float wy0 = 1.0f - ly, wy1 = ly;
        off0[sub] = iy0 * FW + base;
        off1[sub] = iy1 * FW + base;
        w4[sub] = make_float4(wy0 * wxl * 0.25f, wy0 * wxr * 0.25f,
                              wy1 * wxl * 0.25f, wy1 * wxr * 0.25f);
    }

    // ---- ISSUE PHASE: all scattered loads back-to-back, zero FMAs between.
    const float* fb = feat + (size_t)cbase * (FH * FW);
    const float* f0 = fb + (size_t)cslot * (FH * FW);
    const float* f1 = fb + (size_t)(cslot + 5) * (FH * FW);
    const float* f2 = fb + (size_t)(cslot + 10) * (FH * FW);
    f2u r0[8], r1[8], r2[8], r3[8];
#pragma unroll
    for (int sub = 0; sub < 4; ++sub) {
        r0[2 * sub]     = *(const f2u*)(f0 + off0[sub]);
        r0[2 * sub + 1] = *(const f2u*)(f0 + off1[sub]);
    }
#pragma unroll
    for (int sub = 0; sub < 4; ++sub) {
        r1[2 * sub]     = *(const f2u*)(f1 + off0[sub]);
        r1[2 * sub + 1] = *(const f2u*)(f1 + off1[sub]);
    }
#pragma unroll
    for (int sub = 0; sub < 4; ++sub) {
        r2[2 * sub]     = *(const f2u*)(f2 + off0[sub]);
        r2[2 * sub + 1] = *(const f2u*)(f2 + off1[sub]);
    }
    const bool has4 = (cslot == 0);
    if (has4) {                             // exec-masked: no traffic for cslot>0
        const float* f3 = fb + (size_t)15 * (FH * FW);
#pragma unroll
        for (int sub = 0; sub < 4; ++sub) {
            r3[2 * sub]     = *(const f2u*)(f3 + off0[sub]);
            r3[2 * sub + 1] = *(const f2u*)(f3 + off1[sub]);
        }
    }

    // ---- COMPUTE PHASE: FMAs in load-issue order (in-order vmcnt retire).
    float a0 = 0.0f, a1 = 0.0f, a2 = 0.0f;
#pragma unroll
    for (int sub = 0; sub < 4; ++sub) {
        a0 += w4[sub].x * r0[2 * sub].x + w4[sub].y * r0[2 * sub].y
            + w4[sub].z * r0[2 * sub + 1].x + w4[sub].w * r0[2 * sub + 1].y;
    }
#pragma unroll
    for (int sub = 0; sub < 4; ++sub) {
        a1 += w4[sub].x * r1[2 * sub].x + w4[sub].y * r1[2 * sub].y
            + w4[sub].z * r1[2 * sub + 1].x + w4[sub].w * r1[2 * sub + 1].y;
    }
#pragma unroll
    for (int sub = 0; sub < 4; ++sub) {
        a2 += w4[sub].x * r2[2 * sub].x + w4[sub].y * r2[2 * sub].y
            + w4[sub].z * r2[2 * sub + 1].x + w4[sub].w * r2[2 * sub + 1].y;
    }
    oblk[cslot * 49 + p] = a0;
    oblk[(cslot + 5) * 49 + p] = a1;
    oblk[(cslot + 10) * 49 + p] = a2;

    if (has4) {
        float a3 = 0.0f;
#pragma unroll
        for (int sub = 0; sub < 4; ++sub) {
            a3 += w4[sub].x * r3[2 * sub].x + w4[sub].y * r3[2 * sub].y
                + w4[sub].z * r3[2 * sub + 1].x + w4[sub].w * r3[2 * sub + 1].y;
        }
        oblk[15 * 49 + p] = a3;
    }
}

extern "C" void kernel_launch(void* const* d_in, const int* in_sizes, int n_in,
                              void* d_out, int out_size, void* d_ws, size_t ws_size,
                              hipStream_t stream) {
    const float* feature    = (const float*)d_in[0];
    const float* objectness = (const float*)d_in[1];
    const float* deltas     = (const float*)d_in[2];
    const float* anchors    = (const float*)d_in[3];
    Ws* ws = (Ws*)d_ws;
    uint32_t* hist = (uint32_t*)ws->mask;   // alias: hist lives in (pre-)mask space
    float* out = (float*)d_out;

    hipLaunchKernelGGL(zero_k, dim3(1), dim3(1024), 0, stream, ws);
    hipLaunchKernelGGL(hist_k, dim3(256), dim3(256), 0, stream, objectness, hist);
    hipLaunchKernelGGL(gather_k, dim3((N_ANCH / 4 + 255) / 256), dim3(256), 0, stream,
                       objectness, hist, ws);
    hipLaunchKernelGGL(rank_decode_k, dim3(CAP / (256 / TPE)), dim3(256), 0, stream,
                       deltas, anchors, ws);
    hipLaunchKernelGGL(nms_mask_k, dim3(K_PRE), dim3(256), 0, stream, ws);
    hipLaunchKernelGGL(nms_scan_k, dim3(1), dim3(512), 0, stream, ws);
    hipLaunchKernelGGL(roi_k, dim3(16 * K_POST), dim3(256), 0, stream, feature, ws, out);
}